// Round 20
// baseline (279.912 us; speedup 1.0000x reference)
//
#include <hip/hip_runtime.h>

// MFMA f16 conv pipeline, round 20.
// Round-19: baseline restored (219.5us). conv1 (~95us) is barrier-bound.
// New: conv1_wave — ZERO barriers via wave-private LDS rolling windows.
// Each wave owns a 6-row x 38-px x 16-ic f16 window (9.1KB) for its
// (pooled-row strip, 32-px range); DS ops are in-order per wave, so
// compute-reads -> overwrite-writes need no sync. Staging keeps the proven
// float4 + quad-shuffle-transpose + ds_write_b64 pattern (5 loads/lane in
// flight — not the falsified scalar gather). Loads(t+1) issue before
// compute(t). 73KB LDS/block -> 2 blocks/CU, 16 independent waves/CU.
//
// Layouts (CDNA4):
//   16x16x32: A/B k=(lane>>4)*8+j, m/n=lane&15; D col=lane&15, row=(lane>>4)*4+reg
//   32x32x16: A/B k=(lane>>5)*8+j, m/n=lane&31; D col=lane&31,
//             row=(reg&3)+8*(reg>>2)+4*(lane>>5)

typedef _Float16 f16;
typedef _Float16 f16x8 __attribute__((ext_vector_type(8)));
typedef _Float16 f16x4 __attribute__((ext_vector_type(4)));
typedef float f32x4 __attribute__((ext_vector_type(4)));
typedef float f32x16 __attribute__((ext_vector_type(16)));

// ---------------- pack_all: conv A-frags + wl1 -> f16 -------------------------
__global__ __launch_bounds__(512)
void pack_all(const float* __restrict__ w1, const float* __restrict__ w2,
              const float* __restrict__ w3, const float* __restrict__ w4,
              const float* __restrict__ wl1, f16* __restrict__ apack,
              f16* __restrict__ wl1h) {
  if (blockIdx.x >= 189) {
    int i = ((blockIdx.x - 189) * 512 + threadIdx.x) * 4;   // 256 blocks
    float4 v = *(const float4*)(wl1 + i);
    f16x4 h = { (f16)v.x, (f16)v.y, (f16)v.z, (f16)v.w };
    *(f16x4*)(wl1h + i) = h;
    return;
  }
  int idx = blockIdx.x * 512 + threadIdx.x;
  int frag = idx >> 9;
  int e = idx & 511;
  int lane = e >> 3, j = e & 7;
  float v = 0.f;
  if (frag < 9) {
    int kh = frag / 3, kw = frag % 3;
    int oc = lane & 31;
    int ic = (lane >> 5) * 8 + j;
    if (ic < 12) v = w1[((oc * 12 + ic) * 3 + kh) * 3 + kw];
  } else if (frag < 45) {
    int f = frag - 9;            // conv2 32x32
    int ocg = f & 1;
    int sk = f >> 1;
    int ks = sk & 1, sh = sk >> 1;
    int kh = sh / 3, kw = sh % 3;
    int oc = ocg * 32 + (lane & 31);
    int ic = ks * 16 + (lane >> 5) * 8 + j;
    v = w2[((oc * 32 + ic) * 3 + kh) * 3 + kw];
  } else if (frag < 117) {
    int f = frag - 45;           // conv3 32x32
    int ocg = f & 1;
    int sk = f >> 1;
    int ks = sk & 3, sh = sk >> 2;
    int kh = sh / 3, kw = sh % 3;
    int oc = ocg * 32 + (lane & 31);
    int ic = ks * 16 + (lane >> 5) * 8 + j;
    v = w3[((oc * 64 + ic) * 3 + kh) * 3 + kw];
  } else {
    int f = frag - 117;          // conv4 16x16
    int sk = f >> 2, og = f & 3;
    int sh = sk >> 1, ks = sk & 1;
    int kh = sh / 3, kw = sh % 3;
    int row16 = lane & 15, kg = lane >> 4;
    int oc = og * 16 + row16;
    int ic = ks * 32 + kg * 8 + j;
    v = w4[((oc * 64 + ic) * 3 + kh) * 3 + kw];
  }
  apack[idx] = (f16)v;
}

// ---------------- conv1_wave: wave-private LDS windows, ZERO barriers ---------
// Wave = (pooled-row strip of TPW=8, 32-px range). Private window: 6 row-slots
// x 38 px x 16 ic f16, PADB=40 (b128 reads 8 distinct banks/phase). Per tile:
// stage 2 new rows (2 rows x 10 four-px chunks = 20 tasks, 4 groups x 5 iters),
// compute 12 b128 + 18 MFMA-32x32x16, pool+store. Loads(t+1) before compute(t);
// writes after compute (in-order DS per wave makes read->overwrite safe).
__global__ __launch_bounds__(512, 4)
void conv1_wave(const float* __restrict__ x, const f16* __restrict__ apack,
                const float* __restrict__ bias, f16* __restrict__ hout) {
  constexpr int W = 128, H = 128;
  constexpr int PADB = 40, PXS = 38, ROWB = PXS * PADB;  // 1520 B/row-slot
  constexpr int TPW = 8;
  __shared__ char smem[8 * 6 * ROWB];                    // 72960 B -> 2 blk/CU
  const int tid = threadIdx.x, n = blockIdx.y;
  const int w = tid >> 6, l = tid & 63;
  char* my = smem + w * (6 * ROWB);
  const int pxr = w & 3;                                 // px range (32 each)
  const int pr0 = (blockIdx.x * 2 + (w >> 2)) * 8;       // pooled-row strip
  const int g = l >> 4, l16 = l & 15;                    // stage group / ic lane
  const int Q = l16 >> 2, q = l16 & 3;                   // quad, lane-in-quad
  const int ln = l & 31, hi = l >> 5;                    // MFMA n-lane / k-half
  const int gpxb = pxr * 32;

  f16x8 A[9];
#pragma unroll
  for (int ks = 0; ks < 9; ++ks)
    A[ks] = *(const f16x8*)(apack + ((ks << 9) + (l << 3)));

  // task (0..19) -> rowl = task/10, chunk c = task%10.
  // c==0: gpx0 = gpxb-4 (left halo, only q==3 -> px_local 0)
  // c>=1: gpx0 = gpxb+4*(c-1), px_local = 1+4*(c-1)+q  (1..36)
  float4 a[5];
  auto load2 = [&](int rbase) {
#pragma unroll
    for (int it = 0; it < 5; ++it) {
      const int task = it * 4 + g;
      const int rowl = task / 10, c = task - rowl * 10;
      const int ri = rbase + rowl;
      const int gpx0 = (c == 0) ? (gpxb - 4) : (gpxb + 4 * (c - 1));
      float4 v = make_float4(0.f, 0.f, 0.f, 0.f);
      if (l16 < 12 && ri >= 0 && ri < H && gpx0 >= 0 && gpx0 < W)
        v = *(const float4*)(x + ((size_t)(n * 12 + l16) * H + ri) * W + gpx0);
      a[it] = v;
    }
  };
  auto write2 = [&](int sA, int sB) {
#pragma unroll
    for (int it = 0; it < 5; ++it) {
      const int task = it * 4 + g;
      const int rowl = task / 10, c = task - rowl * 10;
      float4 t1, t2;
      {
        float sx = __shfl_xor(a[it].x, 1), sy = __shfl_xor(a[it].y, 1);
        float sz = __shfl_xor(a[it].z, 1), sw = __shfl_xor(a[it].w, 1);
        bool odd = q & 1;
        t1.x = odd ? sy : a[it].x;  t1.y = odd ? a[it].y : sx;
        t1.z = odd ? sw : a[it].z;  t1.w = odd ? a[it].w : sz;
      }
      {
        float sx = __shfl_xor(t1.x, 2), sy = __shfl_xor(t1.y, 2);
        float sz = __shfl_xor(t1.z, 2), sw = __shfl_xor(t1.w, 2);
        bool hi2 = q & 2;
        t2.x = hi2 ? sz : t1.x;  t2.y = hi2 ? sw : t1.y;
        t2.z = hi2 ? t1.z : sx;  t2.w = hi2 ? t1.w : sy;
      }
      f16x4 hv = { (f16)t2.x, (f16)t2.y, (f16)t2.z, (f16)t2.w };
      const int slot = rowl ? sB : sA;
      const int pxl = (c == 0) ? 0 : (1 + 4 * (c - 1) + q);
      if (c > 0 || q == 3)
        *(f16x4*)(my + slot * ROWB + pxl * PADB + Q * 8) = hv;
    }
  };

  // prologue: rows 2*pr0-1 .. 2*pr0+4 -> slots 0..5
  load2(2 * pr0 - 1);  write2(0, 1);
  load2(2 * pr0 + 1);  write2(2, 3);
  load2(2 * pr0 + 3);  write2(4, 5);

  int s0 = 0;                            // slot of row 2*pr - 1
  for (int t = 0; t < TPW; ++t) {
    const int pr = pr0 + t;
    if (t + 1 < TPW) load2(2 * pr + 5);  // rows 2pr+5, 2pr+6 (issue early)

    f32x16 acc0 = (f32x16)0.f, acc1 = (f32x16)0.f;
#pragma unroll
    for (int kw = 0; kw < 3; ++kw) {
      const char* bcol = my + (ln + kw) * PADB + hi * 16;
      f16x8 R[4];
#pragma unroll
      for (int j = 0; j < 4; ++j) {
        int sl = s0 + j; if (sl >= 6) sl -= 6;
        R[j] = *(const f16x8*)(bcol + sl * ROWB);
      }
#pragma unroll
      for (int kh = 0; kh < 3; ++kh) {
        acc0 = __builtin_amdgcn_mfma_f32_32x32x16_f16(A[kh * 3 + kw], R[kh],     acc0, 0, 0, 0);
        acc1 = __builtin_amdgcn_mfma_f32_32x32x16_f16(A[kh * 3 + kw], R[kh + 1], acc1, 0, 0, 0);
      }
    }
    // epilogue: pool 2x2, bias, relu, NHWC f16 store (OC=32)
#pragma unroll
    for (int gg = 0; gg < 4; ++gg) {
      float v[4];
#pragma unroll
      for (int c = 0; c < 4; ++c) {
        float m = fmaxf(acc0[gg * 4 + c], acc1[gg * 4 + c]);
        v[c] = fmaxf(m, __shfl_xor(m, 1));
      }
      if ((l & 1) == 0) {
        const int pw = (gpxb + ln) >> 1;
        const int oc0 = gg * 8 + hi * 4;
        f16x4 pk;
#pragma unroll
        for (int c = 0; c < 4; ++c)
          pk[c] = (f16)fmaxf(v[c] + bias[oc0 + c], 0.f);
        *(f16x4*)(hout + (((size_t)(n * 64 + pr) * 64 + pw) * 32 + oc0)) = pk;
      }
    }
    if (t + 1 < TPW) {                   // overwrite 2 oldest rows (after reads)
      int sB = s0 + 1; if (sB >= 6) sB -= 6;
      write2(s0, sB);
    }
    s0 += 2; if (s0 >= 6) s0 -= 6;
  }
}

// ---------------- conv2: rolling-window multi-tile, 32x32x16 ------------------
__global__ __launch_bounds__(256)
void conv2_roll(const f16* __restrict__ hin, const f16* __restrict__ apack,
                const float* __restrict__ bias, f16* __restrict__ hout) {
  constexpr int C = 32, W = 64, H = 64;
  constexpr int PADB = 80, ROWB = 66 * PADB;
  constexpr int TPB = 4;
  __shared__ char smem[6 * ROWB];               // 31680 B
  const int tid = threadIdx.x;
  const int n = blockIdx.y;
  const int R0 = blockIdx.x * (TPB * 4);

  auto chunk_ld = [&](int c, int rbase) -> float4 {
    int rowl = c / 264, rem = c - rowl * 264;
    int px = rem >> 2, kc = rem & 3;
    int ri = rbase + rowl, gx = px - 1;
    float4 v = make_float4(0.f, 0.f, 0.f, 0.f);
    if (ri >= 0 && ri < H && gx >= 0 && gx < W)
      v = *(const float4*)(hin + (((size_t)(n * H + ri) * W + gx) * C + kc * 8));
    return v;
  };
  auto chunk_st = [&](int c, int sbase, float4 v) {
    int rowl = c / 264, rem = c - rowl * 264;
    int px = rem >> 2, kc = rem & 3;
    int slot = sbase + rowl; if (slot >= 6) slot -= 6;
    *(float4*)(smem + slot * ROWB + px * PADB + kc * 16) = v;
  };

  {
    float4 a[7];
#pragma unroll
    for (int it = 0; it < 7; ++it) {
      int c = tid + it * 256;
      a[it] = (c < 1584) ? chunk_ld(c, R0 - 1) : make_float4(0.f, 0.f, 0.f, 0.f);
    }
#pragma unroll
    for (int it = 0; it < 7; ++it) {
      int c = tid + it * 256;
      if (c < 1584) chunk_st(c, 0, a[it]);
    }
  }
  __syncthreads();

  const int wv = tid >> 6, l = tid & 63;
  const int rp = wv >> 1;
  const int pxb = (wv & 1) * 32;
  const int rl0 = rp * 2;
  const int ln = l & 31;
  const int hi = l >> 5;

  float4 a[5];
  int s04 = 0;
  for (int t = 0; t < TPB; ++t) {
    if (t + 1 < TPB) {
#pragma unroll
      for (int it = 0; it < 5; ++it) {
        int c = tid + it * 256;
        a[it] = (c < 1056) ? chunk_ld(c, R0 + 4 * t + 5)
                           : make_float4(0.f, 0.f, 0.f, 0.f);
      }
    }
    f32x16 acc[2][2];
    acc[0][0] = (f32x16)0.f; acc[0][1] = (f32x16)0.f;
    acc[1][0] = (f32x16)0.f; acc[1][1] = (f32x16)0.f;
#pragma unroll
    for (int sh = 0; sh < 9; ++sh) {
      const int kh = sh / 3, kw = sh % 3;
      f16x8 A[2][2];
#pragma unroll
      for (int ks = 0; ks < 2; ++ks)
#pragma unroll
        for (int ocg = 0; ocg < 2; ++ocg)
          A[ks][ocg] = *(const f16x8*)(apack + ((((sh * 2 + ks) * 2 + ocg) << 9) + (l << 3)));
#pragma unroll
      for (int rowi = 0; rowi < 2; ++rowi) {
        int sl = s04 + rl0 + rowi + kh; if (sl >= 6) sl -= 6;
        const char* base = smem + sl * ROWB + (pxb + ln + kw) * PADB + hi * 16;
#pragma unroll
        for (int ks = 0; ks < 2; ++ks) {
          f16x8 B = *(const f16x8*)(base + ks * 32);
          acc[rowi][0] = __builtin_amdgcn_mfma_f32_32x32x16_f16(A[ks][0], B, acc[rowi][0], 0, 0, 0);
          acc[rowi][1] = __builtin_amdgcn_mfma_f32_32x32x16_f16(A[ks][1], B, acc[rowi][1], 0, 0, 0);
        }
      }
    }
    {
      const int pr = (R0 >> 1) + 2 * t + rp;
#pragma unroll
      for (int ocg = 0; ocg < 2; ++ocg) {
#pragma unroll
        for (int gg = 0; gg < 4; ++gg) {
          float v[4];
#pragma unroll
          for (int c = 0; c < 4; ++c) {
            float m = fmaxf(acc[0][ocg][gg * 4 + c], acc[1][ocg][gg * 4 + c]);
            v[c] = fmaxf(m, __shfl_xor(m, 1));
          }
          if ((l & 1) == 0) {
            const int pw = (pxb + ln) >> 1;
            const int oc0 = ocg * 32 + gg * 8 + hi * 4;
            f16x4 pk;
#pragma unroll
            for (int c = 0; c < 4; ++c)
              pk[c] = (f16)fmaxf(v[c] + bias[oc0 + c], 0.f);
            *(f16x4*)(hout + (((size_t)(n * 32 + pr) * 32 + pw) * 64 + oc0)) = pk;
          }
        }
      }
    }
    __syncthreads();
    if (t + 1 < TPB) {
#pragma unroll
      for (int it = 0; it < 5; ++it) {
        int c = tid + it * 256;
        if (c < 1056) chunk_st(c, s04, a[it]);
      }
      __syncthreads();
    }
    s04 += 4; if (s04 >= 6) s04 -= 6;
  }
}

// ---------------- conv3: one-shot 32x32x16 ------------------------------------
template<int C, int W, int H, int BR, int PADB>
__global__ __launch_bounds__(256)
void conv_shift32(const f16* __restrict__ hin, const f16* __restrict__ apack,
                  const float* __restrict__ bias, f16* __restrict__ hout) {
  constexpr int KS16 = C / 16;
  constexpr int SR = BR + 2;
  constexpr int ROWB = (W + 2) * PADB;
  __shared__ char smem[SR * ROWB];
  const int tid = threadIdx.x;
  const int n = blockIdx.y;
  const int r0 = blockIdx.x * BR;
  constexpr int CPC = C / 8;
  constexpr int TOTC = SR * (W + 2) * CPC;
  constexpr int NITER = (TOTC + 255) / 256;
  {
    float4 stg[NITER];
#pragma unroll
    for (int it = 0; it < NITER; ++it) {
      const int t = tid + it * 256;
      float4 v = make_float4(0.f, 0.f, 0.f, 0.f);
      if (t < TOTC) {
        int sr = t / ((W + 2) * CPC);
        int rem = t - sr * ((W + 2) * CPC);
        int px = rem / CPC;
        int kc = rem - px * CPC;
        int ri = r0 + sr - 1;
        int gx = px - 1;
        if (ri >= 0 && ri < H && gx >= 0 && gx < W)
          v = *(const float4*)(hin + (((size_t)(n * H + ri) * W + gx) * C + kc * 8));
      }
      stg[it] = v;
    }
#pragma unroll
    for (int it = 0; it < NITER; ++it) {
      const int t = tid + it * 256;
      if (t < TOTC) {
        int sr = t / ((W + 2) * CPC);
        int rem = t - sr * ((W + 2) * CPC);
        int px = rem / CPC;
        int kc = rem - px * CPC;
        *(float4*)(smem + sr * ROWB + px * PADB + kc * 16) = stg[it];
      }
    }
  }
  __syncthreads();

  const int wv = tid >> 6, l = tid & 63;
  constexpr int WPP = W / 32;
  const int rp = wv / WPP;
  const int pxb = (wv % WPP) * 32;
  const int rl0 = rp * 2;
  const int ln = l & 31;
  const int hi = l >> 5;
  const int px0 = pxb + ln;

  f32x16 acc[2][2];
  acc[0][0] = (f32x16)0.f; acc[0][1] = (f32x16)0.f;
  acc[1][0] = (f32x16)0.f; acc[1][1] = (f32x16)0.f;

#pragma unroll
  for (int sh = 0; sh < 9; ++sh) {
    const int kh = sh / 3, kw = sh % 3;
    f16x8 A[KS16][2];
#pragma unroll
    for (int ks = 0; ks < KS16; ++ks)
#pragma unroll
      for (int ocg = 0; ocg < 2; ++ocg)
        A[ks][ocg] = *(const f16x8*)(apack + ((((sh * KS16 + ks) * 2 + ocg) << 9) + (l << 3)));
#pragma unroll
    for (int rowi = 0; rowi < 2; ++rowi) {
      const char* base = smem + (rl0 + rowi + kh) * ROWB + (px0 + kw) * PADB + hi * 16;
#pragma unroll
      for (int ks = 0; ks < KS16; ++ks) {
        f16x8 B = *(const f16x8*)(base + ks * 32);
        acc[rowi][0] = __builtin_amdgcn_mfma_f32_32x32x16_f16(A[ks][0], B, acc[rowi][0], 0, 0, 0);
        acc[rowi][1] = __builtin_amdgcn_mfma_f32_32x32x16_f16(A[ks][1], B, acc[rowi][1], 0, 0, 0);
      }
    }
  }
  constexpr int PH = H / 2, PW = W / 2;
  const int pr = blockIdx.x * (BR / 2) + rp;
#pragma unroll
  for (int ocg = 0; ocg < 2; ++ocg) {
#pragma unroll
    for (int gg = 0; gg < 4; ++gg) {
      float v[4];
#pragma unroll
      for (int c = 0; c < 4; ++c) {
        float m = fmaxf(acc[0][ocg][gg * 4 + c], acc[1][ocg][gg * 4 + c]);
        v[c] = fmaxf(m, __shfl_xor(m, 1));
      }
      if ((l & 1) == 0) {
        const int pw = (pxb + ln) >> 1;
        const int oc0 = ocg * 32 + gg * 8 + hi * 4;
        f16x4 pk;
#pragma unroll
        for (int c = 0; c < 4; ++c)
          pk[c] = (f16)fmaxf(v[c] + bias[oc0 + c], 0.f);
        *(f16x4*)(hout + (((size_t)(n * PH + pr) * PW + pw) * 64 + oc0)) = pk;
      }
    }
  }
}

// ---------------- tail_fused: conv4 + maxpool + FC head, one block per image --
__global__ __launch_bounds__(512)
void tail_fused(const f16* __restrict__ hin, const f16* __restrict__ apack4,
                const float* __restrict__ bias, const f16* __restrict__ wl1h,
                const float* __restrict__ bl1, const float* __restrict__ wl2,
                const float* __restrict__ bl2, float* __restrict__ out) {
  constexpr int C = 64, W = 16, H = 16;
  constexpr int PADB = 144, ROWB = 18 * PADB;   // 2592 B/row-slot
  __shared__ char smem[18 * ROWB];              // 46656 B
  __shared__ float hbuf[4096];
  __shared__ float red[4 * 128];
  __shared__ float red2[128];
  const int tid = threadIdx.x;
  const int n = blockIdx.x;

  constexpr int CPC = 8, TOTC = 18 * 18 * CPC;
  {
    float4 stg[6];
#pragma unroll
    for (int it = 0; it < 6; ++it) {
      const int t = tid + it * 512;
      float4 v = make_float4(0.f, 0.f, 0.f, 0.f);
      if (t < TOTC) {
        int sr = t / (18 * CPC);
        int rem = t - sr * (18 * CPC);
        int px = rem / CPC;
        int kc = rem - px * CPC;
        int ri = sr - 1, gx = px - 1;
        if (ri >= 0 && ri < H && gx >= 0 && gx < W)
          v = *(const float4*)(hin + (((size_t)(n * H + ri) * W + gx) * C + kc * 8));
      }
      stg[it] = v;
    }
#pragma unroll
    for (int it = 0; it < 6; ++it) {
      const int t = tid + it * 512;
      if (t < TOTC) {
        int sr = t / (18 * CPC);
        int rem = t - sr * (18 * CPC);
        int px = rem / CPC;
        int kc = rem - px * CPC;
        *(float4*)(smem + sr * ROWB + px * PADB + kc * 16) = stg[it];
      }
    }
  }
  __syncthreads();

  {
    const int wv = tid >> 6, l = tid & 63;
    const int lp = l & 15, kg = l >> 4;
    const int rl0 = wv * 2;

    f32x4 acc[2][4];
#pragma unroll
    for (int a = 0; a < 2; ++a)
#pragma unroll
      for (int o = 0; o < 4; ++o) acc[a][o] = (f32x4){0.f, 0.f, 0.f, 0.f};

#pragma unroll
    for (int sh = 0; sh < 9; ++sh) {
      const int kh = sh / 3, kw = sh % 3;
      f16x8 A[2][4];
#pragma unroll
      for (int ks = 0; ks < 2; ++ks)
#pragma unroll
        for (int og = 0; og < 4; ++og)
          A[ks][og] = *(const f16x8*)(apack4 + ((((sh * 2 + ks) * 4 + og) << 9) + (l << 3)));
#pragma unroll
      for (int rowi = 0; rowi < 2; ++rowi) {
        const char* base = smem + (rl0 + rowi + kh) * ROWB;
#pragma unroll
        for (int ks = 0; ks < 2; ++ks) {
          f16x8 B = *(const f16x8*)(base + (lp + kw) * PADB + ks * 64 + kg * 16);
#pragma unroll
          for (int og = 0; og < 4; ++og)
            acc[rowi][og] =
                __builtin_amdgcn_mfma_f32_16x16x32_f16(A[ks][og], B, acc[rowi][og], 0, 0, 0);
        }
      }
    }
#pragma unroll
    for (int og = 0; og < 4; ++og) {
      float v[4];
#pragma unroll
      for (int c = 0; c < 4; ++c) {
        float m = fmaxf(acc[0][og][c], acc[1][og][c]);
        v[c] = fmaxf(m, __shfl_xor(m, 1));
      }
      if ((l & 1) == 0) {
        const int pw = lp >> 1;
        const int oc0 = og * 16 + kg * 4;
#pragma unroll
        for (int c = 0; c < 4; ++c)
          hbuf[(oc0 + c) * 64 + wv * 8 + pw] = fmaxf(v[c] + bias[oc0 + c], 0.f);
      }
    }
  }
  __syncthreads();

  {
    const int nn = tid & 127;
    const int ks = tid >> 7;
    const f16x8* wp = (const f16x8*)(wl1h + (size_t)nn * 4096 + ks * 1024);
    const float4* xr = (const float4*)(&hbuf[ks * 1024]);
    float s = 0.f;
#pragma unroll 4
    for (int i = 0; i < 128; ++i) {
      f16x8 w8 = wp[i];
      float4 a0 = xr[2 * i], a1 = xr[2 * i + 1];
      s = fmaf((float)w8[0], a0.x, fmaf((float)w8[1], a0.y,
          fmaf((float)w8[2], a0.z, fmaf((float)w8[3], a0.w, s))));
      s = fmaf((float)w8[4], a1.x, fmaf((float)w8[5], a1.y,
          fmaf((float)w8[6], a1.z, fmaf((float)w8[7], a1.w, s))));
    }
    red[ks * 128 + nn] = s;
  }
  __syncthreads();
  if (tid < 128) {
    float h = bl1[tid] + red[tid] + red[128 + tid] + red[256 + tid] + red[384 + tid];
    h = fmaxf(h, 0.f);
    red2[tid] = h * (wl2[tid] + 20.0f * wl2[256 + tid]);
  }
  __syncthreads();
#pragma unroll
  for (int s = 64; s > 0; s >>= 1) {
    if (tid < s) red2[tid] += red2[tid + s];
    __syncthreads();
  }
  if (tid == 0) out[n] = red2[0] + bl2[0] + 20.0f * bl2[2];
}

extern "C" void kernel_launch(void* const* d_in, const int* in_sizes, int n_in,
                              void* d_out, int out_size, void* d_ws, size_t ws_size,
                              hipStream_t stream) {
  const float* x   = (const float*)d_in[0];
  const float* w1  = (const float*)d_in[1];
  const float* b1  = (const float*)d_in[2];
  const float* w2  = (const float*)d_in[3];
  const float* b2  = (const float*)d_in[4];
  const float* w3  = (const float*)d_in[5];
  const float* b3  = (const float*)d_in[6];
  const float* w4  = (const float*)d_in[7];
  const float* b4  = (const float*)d_in[8];
  const float* wl1 = (const float*)d_in[9];
  const float* bl1 = (const float*)d_in[10];
  const float* wl2 = (const float*)d_in[11];
  const float* bl2 = (const float*)d_in[12];
  float* out = (float*)d_out;
  char* ws = (char*)d_ws;

  f16* apack = (f16*)ws;
  f16* wl1h  = (f16*)(ws + 524288u);
  f16* h1 = (f16*)(ws + 2097152u);
  f16* h2 = (f16*)(ws + 69206016u);
  f16* h3 = (f16*)(ws + 102760448u);

  pack_all<<<445, 512, 0, stream>>>(w1, w2, w3, w4, wl1, apack, wl1h);
  conv1_wave<<<dim3(4, 256), 512, 0, stream>>>(x, apack, b1, h1);
  conv2_roll<<<dim3(4, 256), 256, 0, stream>>>(h1, apack + 9 * 512, b2, h2);
  conv_shift32<64, 32, 32, 8, 144><<<dim3(4, 256), 256, 0, stream>>>(
      h2, apack + 45 * 512, b3, h3);
  tail_fused<<<256, 512, 0, stream>>>(h3, apack + 117 * 512, b4, wl1h,
                                      bl1, wl2, bl2, out);
}

// Round 21
// 219.298 us; speedup vs baseline: 1.2764x; 1.2764x over previous
//
#include <hip/hip_runtime.h>

// MFMA f16 conv pipeline, round 21 = round-19/15 config restored (best: 219.5us).
// Round-20 post-mortem: conv1_wave falsified (161us vs 95): barrier removal
// didn't remove the per-wave load->shfl->ds_write->ds_read->MFMA dependence
// chain, and 73KB LDS halved TLP. Third falsified conv1 rewrite; the shared
// rolling window (8 waves amortize staging, 4 blk/CU TLP) is the local optimum.
//
// Layouts (CDNA4):
//   16x16x32: A/B k=(lane>>4)*8+j, m/n=lane&15; D col=lane&15, row=(lane>>4)*4+reg
//   32x32x16: A/B k=(lane>>5)*8+j, m/n=lane&31; D col=lane&31,
//             row=(reg&3)+8*(reg>>2)+4*(lane>>5)

typedef _Float16 f16;
typedef _Float16 f16x8 __attribute__((ext_vector_type(8)));
typedef _Float16 f16x4 __attribute__((ext_vector_type(4)));
typedef float f32x4 __attribute__((ext_vector_type(4)));
typedef float f32x16 __attribute__((ext_vector_type(16)));

// ---------------- pack_all: conv A-frags + wl1 -> f16 -------------------------
__global__ __launch_bounds__(512)
void pack_all(const float* __restrict__ w1, const float* __restrict__ w2,
              const float* __restrict__ w3, const float* __restrict__ w4,
              const float* __restrict__ wl1, f16* __restrict__ apack,
              f16* __restrict__ wl1h) {
  if (blockIdx.x >= 189) {
    int i = ((blockIdx.x - 189) * 512 + threadIdx.x) * 4;   // 256 blocks
    float4 v = *(const float4*)(wl1 + i);
    f16x4 h = { (f16)v.x, (f16)v.y, (f16)v.z, (f16)v.w };
    *(f16x4*)(wl1h + i) = h;
    return;
  }
  int idx = blockIdx.x * 512 + threadIdx.x;
  int frag = idx >> 9;
  int e = idx & 511;
  int lane = e >> 3, j = e & 7;
  float v = 0.f;
  if (frag < 9) {
    int kh = frag / 3, kw = frag % 3;
    int oc = lane & 31;
    int ic = (lane >> 5) * 8 + j;
    if (ic < 12) v = w1[((oc * 12 + ic) * 3 + kh) * 3 + kw];
  } else if (frag < 45) {
    int f = frag - 9;            // conv2 32x32
    int ocg = f & 1;
    int sk = f >> 1;
    int ks = sk & 1, sh = sk >> 1;
    int kh = sh / 3, kw = sh % 3;
    int oc = ocg * 32 + (lane & 31);
    int ic = ks * 16 + (lane >> 5) * 8 + j;
    v = w2[((oc * 32 + ic) * 3 + kh) * 3 + kw];
  } else if (frag < 117) {
    int f = frag - 45;           // conv3 32x32
    int ocg = f & 1;
    int sk = f >> 1;
    int ks = sk & 3, sh = sk >> 2;
    int kh = sh / 3, kw = sh % 3;
    int oc = ocg * 32 + (lane & 31);
    int ic = ks * 16 + (lane >> 5) * 8 + j;
    v = w3[((oc * 64 + ic) * 3 + kh) * 3 + kw];
  } else {
    int f = frag - 117;          // conv4 16x16
    int sk = f >> 2, og = f & 3;
    int sh = sk >> 1, ks = sk & 1;
    int kh = sh / 3, kw = sh % 3;
    int row16 = lane & 15, kg = lane >> 4;
    int oc = og * 16 + row16;
    int ic = ks * 32 + kg * 8 + j;
    v = w4[((oc * 64 + ic) * 3 + kh) * 3 + kw];
  }
  apack[idx] = (f16)v;
}

// ---------------- conv1: 12ch fp32 NCHW -> 32ch NHWC f16, pool ----------------
// TPB=8 rolling 6-slot window, 32x32x16, kw-outer B-share.
__global__ __launch_bounds__(512)
void conv1_mfma(const float* __restrict__ x, const f16* __restrict__ apack,
                const float* __restrict__ bias, f16* __restrict__ hout) {
  constexpr int W = 128, H = 128;
  constexpr int PADB = 48, ROWB = 130 * PADB;
  constexpr int TPB = 8;
  __shared__ char smem[6 * ROWB];               // 37440 B
  const int tid = threadIdx.x;
  const int n = blockIdx.y;
  const int R0 = blockIdx.x * (TPB * 4);

  if (tid < 36) {
    int slot = tid / 6, r = tid % 6;
    int px = (r >= 3) ? 129 : 0;
    int ch = r % 3;
    *(float4*)(smem + slot * ROWB + px * PADB + ch * 16) =
        make_float4(0.f, 0.f, 0.f, 0.f);
  }

  const int g = tid >> 4;
  const int l16 = tid & 15;
  const int Q = l16 >> 2, q = l16 & 3;

  auto load_row = [&](int ri) -> float4 {
    float4 v = make_float4(0.f, 0.f, 0.f, 0.f);
    if (l16 < 12 && ri >= 0 && ri < H)
      v = *(const float4*)(x + ((size_t)(n * 12 + l16) * H + ri) * W + g * 4);
    return v;
  };
  auto xpose_write = [&](float4 av, int slot) {
    float4 t1, t2;
    {
      float sx = __shfl_xor(av.x, 1), sy = __shfl_xor(av.y, 1);
      float sz = __shfl_xor(av.z, 1), sw = __shfl_xor(av.w, 1);
      bool odd = q & 1;
      t1.x = odd ? sy : av.x;  t1.y = odd ? av.y : sx;
      t1.z = odd ? sw : av.z;  t1.w = odd ? av.w : sz;
    }
    {
      float sx = __shfl_xor(t1.x, 2), sy = __shfl_xor(t1.y, 2);
      float sz = __shfl_xor(t1.z, 2), sw = __shfl_xor(t1.w, 2);
      bool hi2 = q & 2;
      t2.x = hi2 ? sz : t1.x;  t2.y = hi2 ? sw : t1.y;
      t2.z = hi2 ? t1.z : sx;  t2.w = hi2 ? t1.w : sy;
    }
    f16x4 h = { (f16)t2.x, (f16)t2.y, (f16)t2.z, (f16)t2.w };
    *(f16x4*)(smem + slot * ROWB + (g * 4 + q + 1) * PADB + Q * 8) = h;
  };

  const int wv = tid >> 6, l = tid & 63;
  const int rp = wv >> 2;
  const int pxb = (wv & 3) * 32;
  const int rl0 = rp * 2;
  const int ln = l & 31;
  const int hi = l >> 5;

  f16x8 A[9];
#pragma unroll
  for (int ks = 0; ks < 9; ++ks)
    A[ks] = *(const f16x8*)(apack + ((ks << 9) + (l << 3)));

  float4 a[6];
#pragma unroll
  for (int i = 0; i < 6; ++i) a[i] = load_row(R0 - 1 + i);
#pragma unroll
  for (int i = 0; i < 6; ++i) xpose_write(a[i], i);
  __syncthreads();

  int s0 = 0;
  for (int t = 0; t < TPB; ++t) {
    if (t + 1 < TPB) {
#pragma unroll
      for (int i = 0; i < 4; ++i) a[i] = load_row(R0 + 4 * t + 5 + i);
    }
    f32x16 acc0 = (f32x16)0.f, acc1 = (f32x16)0.f;
#pragma unroll
    for (int kw = 0; kw < 3; ++kw) {
      const char* bcol = smem + (pxb + ln + kw) * PADB + hi * 16;
      f16x8 R[4];
#pragma unroll
      for (int j = 0; j < 4; ++j) {
        int sl = s0 + rl0 + j; if (sl >= 6) sl -= 6;
        R[j] = *(const f16x8*)(bcol + sl * ROWB);
      }
#pragma unroll
      for (int kh = 0; kh < 3; ++kh) {
        acc0 = __builtin_amdgcn_mfma_f32_32x32x16_f16(A[kh * 3 + kw], R[kh],     acc0, 0, 0, 0);
        acc1 = __builtin_amdgcn_mfma_f32_32x32x16_f16(A[kh * 3 + kw], R[kh + 1], acc1, 0, 0, 0);
      }
    }
    {
      const int pr = (R0 >> 1) + 2 * t + rp;
#pragma unroll
      for (int gg = 0; gg < 4; ++gg) {
        float v[4];
#pragma unroll
        for (int c = 0; c < 4; ++c) {
          float m = fmaxf(acc0[gg * 4 + c], acc1[gg * 4 + c]);
          v[c] = fmaxf(m, __shfl_xor(m, 1));
        }
        if ((l & 1) == 0) {
          const int pw = (pxb + ln) >> 1;
          const int oc0 = gg * 8 + hi * 4;
          f16x4 pk;
#pragma unroll
          for (int c = 0; c < 4; ++c)
            pk[c] = (f16)fmaxf(v[c] + bias[oc0 + c], 0.f);
          *(f16x4*)(hout + (((size_t)(n * 64 + pr) * 64 + pw) * 32 + oc0)) = pk;
        }
      }
    }
    __syncthreads();
    if (t + 1 < TPB) {
#pragma unroll
      for (int i = 0; i < 4; ++i) {
        int sl = s0 + i; if (sl >= 6) sl -= 6;
        xpose_write(a[i], sl);
      }
      __syncthreads();
    }
    s0 += 4; if (s0 >= 6) s0 -= 6;
  }
}

// ---------------- conv2: rolling-window multi-tile, 32x32x16 ------------------
__global__ __launch_bounds__(256)
void conv2_roll(const f16* __restrict__ hin, const f16* __restrict__ apack,
                const float* __restrict__ bias, f16* __restrict__ hout) {
  constexpr int C = 32, W = 64, H = 64;
  constexpr int PADB = 80, ROWB = 66 * PADB;
  constexpr int TPB = 4;
  __shared__ char smem[6 * ROWB];               // 31680 B
  const int tid = threadIdx.x;
  const int n = blockIdx.y;
  const int R0 = blockIdx.x * (TPB * 4);

  auto chunk_ld = [&](int c, int rbase) -> float4 {
    int rowl = c / 264, rem = c - rowl * 264;
    int px = rem >> 2, kc = rem & 3;
    int ri = rbase + rowl, gx = px - 1;
    float4 v = make_float4(0.f, 0.f, 0.f, 0.f);
    if (ri >= 0 && ri < H && gx >= 0 && gx < W)
      v = *(const float4*)(hin + (((size_t)(n * H + ri) * W + gx) * C + kc * 8));
    return v;
  };
  auto chunk_st = [&](int c, int sbase, float4 v) {
    int rowl = c / 264, rem = c - rowl * 264;
    int px = rem >> 2, kc = rem & 3;
    int slot = sbase + rowl; if (slot >= 6) slot -= 6;
    *(float4*)(smem + slot * ROWB + px * PADB + kc * 16) = v;
  };

  {
    float4 a[7];
#pragma unroll
    for (int it = 0; it < 7; ++it) {
      int c = tid + it * 256;
      a[it] = (c < 1584) ? chunk_ld(c, R0 - 1) : make_float4(0.f, 0.f, 0.f, 0.f);
    }
#pragma unroll
    for (int it = 0; it < 7; ++it) {
      int c = tid + it * 256;
      if (c < 1584) chunk_st(c, 0, a[it]);
    }
  }
  __syncthreads();

  const int wv = tid >> 6, l = tid & 63;
  const int rp = wv >> 1;
  const int pxb = (wv & 1) * 32;
  const int rl0 = rp * 2;
  const int ln = l & 31;
  const int hi = l >> 5;

  float4 a[5];
  int s04 = 0;
  for (int t = 0; t < TPB; ++t) {
    if (t + 1 < TPB) {
#pragma unroll
      for (int it = 0; it < 5; ++it) {
        int c = tid + it * 256;
        a[it] = (c < 1056) ? chunk_ld(c, R0 + 4 * t + 5)
                           : make_float4(0.f, 0.f, 0.f, 0.f);
      }
    }
    f32x16 acc[2][2];
    acc[0][0] = (f32x16)0.f; acc[0][1] = (f32x16)0.f;
    acc[1][0] = (f32x16)0.f; acc[1][1] = (f32x16)0.f;
#pragma unroll
    for (int sh = 0; sh < 9; ++sh) {
      const int kh = sh / 3, kw = sh % 3;
      f16x8 A[2][2];
#pragma unroll
      for (int ks = 0; ks < 2; ++ks)
#pragma unroll
        for (int ocg = 0; ocg < 2; ++ocg)
          A[ks][ocg] = *(const f16x8*)(apack + ((((sh * 2 + ks) * 2 + ocg) << 9) + (l << 3)));
#pragma unroll
      for (int rowi = 0; rowi < 2; ++rowi) {
        int sl = s04 + rl0 + rowi + kh; if (sl >= 6) sl -= 6;
        const char* base = smem + sl * ROWB + (pxb + ln + kw) * PADB + hi * 16;
#pragma unroll
        for (int ks = 0; ks < 2; ++ks) {
          f16x8 B = *(const f16x8*)(base + ks * 32);
          acc[rowi][0] = __builtin_amdgcn_mfma_f32_32x32x16_f16(A[ks][0], B, acc[rowi][0], 0, 0, 0);
          acc[rowi][1] = __builtin_amdgcn_mfma_f32_32x32x16_f16(A[ks][1], B, acc[rowi][1], 0, 0, 0);
        }
      }
    }
    {
      const int pr = (R0 >> 1) + 2 * t + rp;
#pragma unroll
      for (int ocg = 0; ocg < 2; ++ocg) {
#pragma unroll
        for (int gg = 0; gg < 4; ++gg) {
          float v[4];
#pragma unroll
          for (int c = 0; c < 4; ++c) {
            float m = fmaxf(acc[0][ocg][gg * 4 + c], acc[1][ocg][gg * 4 + c]);
            v[c] = fmaxf(m, __shfl_xor(m, 1));
          }
          if ((l & 1) == 0) {
            const int pw = (pxb + ln) >> 1;
            const int oc0 = ocg * 32 + gg * 8 + hi * 4;
            f16x4 pk;
#pragma unroll
            for (int c = 0; c < 4; ++c)
              pk[c] = (f16)fmaxf(v[c] + bias[oc0 + c], 0.f);
            *(f16x4*)(hout + (((size_t)(n * 32 + pr) * 32 + pw) * 64 + oc0)) = pk;
          }
        }
      }
    }
    __syncthreads();
    if (t + 1 < TPB) {
#pragma unroll
      for (int it = 0; it < 5; ++it) {
        int c = tid + it * 256;
        if (c < 1056) chunk_st(c, s04, a[it]);
      }
      __syncthreads();
    }
    s04 += 4; if (s04 >= 6) s04 -= 6;
  }
}

// ---------------- conv3: one-shot 32x32x16 ------------------------------------
template<int C, int W, int H, int BR, int PADB>
__global__ __launch_bounds__(256)
void conv_shift32(const f16* __restrict__ hin, const f16* __restrict__ apack,
                  const float* __restrict__ bias, f16* __restrict__ hout) {
  constexpr int KS16 = C / 16;
  constexpr int SR = BR + 2;
  constexpr int ROWB = (W + 2) * PADB;
  __shared__ char smem[SR * ROWB];
  const int tid = threadIdx.x;
  const int n = blockIdx.y;
  const int r0 = blockIdx.x * BR;
  constexpr int CPC = C / 8;
  constexpr int TOTC = SR * (W + 2) * CPC;
  constexpr int NITER = (TOTC + 255) / 256;
  {
    float4 stg[NITER];
#pragma unroll
    for (int it = 0; it < NITER; ++it) {
      const int t = tid + it * 256;
      float4 v = make_float4(0.f, 0.f, 0.f, 0.f);
      if (t < TOTC) {
        int sr = t / ((W + 2) * CPC);
        int rem = t - sr * ((W + 2) * CPC);
        int px = rem / CPC;
        int kc = rem - px * CPC;
        int ri = r0 + sr - 1;
        int gx = px - 1;
        if (ri >= 0 && ri < H && gx >= 0 && gx < W)
          v = *(const float4*)(hin + (((size_t)(n * H + ri) * W + gx) * C + kc * 8));
      }
      stg[it] = v;
    }
#pragma unroll
    for (int it = 0; it < NITER; ++it) {
      const int t = tid + it * 256;
      if (t < TOTC) {
        int sr = t / ((W + 2) * CPC);
        int rem = t - sr * ((W + 2) * CPC);
        int px = rem / CPC;
        int kc = rem - px * CPC;
        *(float4*)(smem + sr * ROWB + px * PADB + kc * 16) = stg[it];
      }
    }
  }
  __syncthreads();

  const int wv = tid >> 6, l = tid & 63;
  constexpr int WPP = W / 32;
  const int rp = wv / WPP;
  const int pxb = (wv % WPP) * 32;
  const int rl0 = rp * 2;
  const int ln = l & 31;
  const int hi = l >> 5;
  const int px0 = pxb + ln;

  f32x16 acc[2][2];
  acc[0][0] = (f32x16)0.f; acc[0][1] = (f32x16)0.f;
  acc[1][0] = (f32x16)0.f; acc[1][1] = (f32x16)0.f;

#pragma unroll
  for (int sh = 0; sh < 9; ++sh) {
    const int kh = sh / 3, kw = sh % 3;
    f16x8 A[KS16][2];
#pragma unroll
    for (int ks = 0; ks < KS16; ++ks)
#pragma unroll
      for (int ocg = 0; ocg < 2; ++ocg)
        A[ks][ocg] = *(const f16x8*)(apack + ((((sh * KS16 + ks) * 2 + ocg) << 9) + (l << 3)));
#pragma unroll
    for (int rowi = 0; rowi < 2; ++rowi) {
      const char* base = smem + (rl0 + rowi + kh) * ROWB + (px0 + kw) * PADB + hi * 16;
#pragma unroll
      for (int ks = 0; ks < KS16; ++ks) {
        f16x8 B = *(const f16x8*)(base + ks * 32);
        acc[rowi][0] = __builtin_amdgcn_mfma_f32_32x32x16_f16(A[ks][0], B, acc[rowi][0], 0, 0, 0);
        acc[rowi][1] = __builtin_amdgcn_mfma_f32_32x32x16_f16(A[ks][1], B, acc[rowi][1], 0, 0, 0);
      }
    }
  }
  constexpr int PH = H / 2, PW = W / 2;
  const int pr = blockIdx.x * (BR / 2) + rp;
#pragma unroll
  for (int ocg = 0; ocg < 2; ++ocg) {
#pragma unroll
    for (int gg = 0; gg < 4; ++gg) {
      float v[4];
#pragma unroll
      for (int c = 0; c < 4; ++c) {
        float m = fmaxf(acc[0][ocg][gg * 4 + c], acc[1][ocg][gg * 4 + c]);
        v[c] = fmaxf(m, __shfl_xor(m, 1));
      }
      if ((l & 1) == 0) {
        const int pw = (pxb + ln) >> 1;
        const int oc0 = ocg * 32 + gg * 8 + hi * 4;
        f16x4 pk;
#pragma unroll
        for (int c = 0; c < 4; ++c)
          pk[c] = (f16)fmaxf(v[c] + bias[oc0 + c], 0.f);
        *(f16x4*)(hout + (((size_t)(n * PH + pr) * PW + pw) * 64 + oc0)) = pk;
      }
    }
  }
}

// ---------------- tail_fused: conv4 + maxpool + FC head, one block per image --
__global__ __launch_bounds__(512)
void tail_fused(const f16* __restrict__ hin, const f16* __restrict__ apack4,
                const float* __restrict__ bias, const f16* __restrict__ wl1h,
                const float* __restrict__ bl1, const float* __restrict__ wl2,
                const float* __restrict__ bl2, float* __restrict__ out) {
  constexpr int C = 64, W = 16, H = 16;
  constexpr int PADB = 144, ROWB = 18 * PADB;   // 2592 B/row-slot
  __shared__ char smem[18 * ROWB];              // 46656 B
  __shared__ float hbuf[4096];
  __shared__ float red[4 * 128];
  __shared__ float red2[128];
  const int tid = threadIdx.x;
  const int n = blockIdx.x;

  constexpr int CPC = 8, TOTC = 18 * 18 * CPC;
  {
    float4 stg[6];
#pragma unroll
    for (int it = 0; it < 6; ++it) {
      const int t = tid + it * 512;
      float4 v = make_float4(0.f, 0.f, 0.f, 0.f);
      if (t < TOTC) {
        int sr = t / (18 * CPC);
        int rem = t - sr * (18 * CPC);
        int px = rem / CPC;
        int kc = rem - px * CPC;
        int ri = sr - 1, gx = px - 1;
        if (ri >= 0 && ri < H && gx >= 0 && gx < W)
          v = *(const float4*)(hin + (((size_t)(n * H + ri) * W + gx) * C + kc * 8));
      }
      stg[it] = v;
    }
#pragma unroll
    for (int it = 0; it < 6; ++it) {
      const int t = tid + it * 512;
      if (t < TOTC) {
        int sr = t / (18 * CPC);
        int rem = t - sr * (18 * CPC);
        int px = rem / CPC;
        int kc = rem - px * CPC;
        *(float4*)(smem + sr * ROWB + px * PADB + kc * 16) = stg[it];
      }
    }
  }
  __syncthreads();

  {
    const int wv = tid >> 6, l = tid & 63;
    const int lp = l & 15, kg = l >> 4;
    const int rl0 = wv * 2;

    f32x4 acc[2][4];
#pragma unroll
    for (int a = 0; a < 2; ++a)
#pragma unroll
      for (int o = 0; o < 4; ++o) acc[a][o] = (f32x4){0.f, 0.f, 0.f, 0.f};

#pragma unroll
    for (int sh = 0; sh < 9; ++sh) {
      const int kh = sh / 3, kw = sh % 3;
      f16x8 A[2][4];
#pragma unroll
      for (int ks = 0; ks < 2; ++ks)
#pragma unroll
        for (int og = 0; og < 4; ++og)
          A[ks][og] = *(const f16x8*)(apack4 + ((((sh * 2 + ks) * 4 + og) << 9) + (l << 3)));
#pragma unroll
      for (int rowi = 0; rowi < 2; ++rowi) {
        const char* base = smem + (rl0 + rowi + kh) * ROWB;
#pragma unroll
        for (int ks = 0; ks < 2; ++ks) {
          f16x8 B = *(const f16x8*)(base + (lp + kw) * PADB + ks * 64 + kg * 16);
#pragma unroll
          for (int og = 0; og < 4; ++og)
            acc[rowi][og] =
                __builtin_amdgcn_mfma_f32_16x16x32_f16(A[ks][og], B, acc[rowi][og], 0, 0, 0);
        }
      }
    }
#pragma unroll
    for (int og = 0; og < 4; ++og) {
      float v[4];
#pragma unroll
      for (int c = 0; c < 4; ++c) {
        float m = fmaxf(acc[0][og][c], acc[1][og][c]);
        v[c] = fmaxf(m, __shfl_xor(m, 1));
      }
      if ((l & 1) == 0) {
        const int pw = lp >> 1;
        const int oc0 = og * 16 + kg * 4;
#pragma unroll
        for (int c = 0; c < 4; ++c)
          hbuf[(oc0 + c) * 64 + wv * 8 + pw] = fmaxf(v[c] + bias[oc0 + c], 0.f);
      }
    }
  }
  __syncthreads();

  {
    const int nn = tid & 127;
    const int ks = tid >> 7;
    const f16x8* wp = (const f16x8*)(wl1h + (size_t)nn * 4096 + ks * 1024);
    const float4* xr = (const float4*)(&hbuf[ks * 1024]);
    float s = 0.f;
#pragma unroll 4
    for (int i = 0; i < 128; ++i) {
      f16x8 w8 = wp[i];
      float4 a0 = xr[2 * i], a1 = xr[2 * i + 1];
      s = fmaf((float)w8[0], a0.x, fmaf((float)w8[1], a0.y,
          fmaf((float)w8[2], a0.z, fmaf((float)w8[3], a0.w, s))));
      s = fmaf((float)w8[4], a1.x, fmaf((float)w8[5], a1.y,
          fmaf((float)w8[6], a1.z, fmaf((float)w8[7], a1.w, s))));
    }
    red[ks * 128 + nn] = s;
  }
  __syncthreads();
  if (tid < 128) {
    float h = bl1[tid] + red[tid] + red[128 + tid] + red[256 + tid] + red[384 + tid];
    h = fmaxf(h, 0.f);
    red2[tid] = h * (wl2[tid] + 20.0f * wl2[256 + tid]);
  }
  __syncthreads();
#pragma unroll
  for (int s = 64; s > 0; s >>= 1) {
    if (tid < s) red2[tid] += red2[tid + s];
    __syncthreads();
  }
  if (tid == 0) out[n] = red2[0] + bl2[0] + 20.0f * bl2[2];
}

extern "C" void kernel_launch(void* const* d_in, const int* in_sizes, int n_in,
                              void* d_out, int out_size, void* d_ws, size_t ws_size,
                              hipStream_t stream) {
  const float* x   = (const float*)d_in[0];
  const float* w1  = (const float*)d_in[1];
  const float* b1  = (const float*)d_in[2];
  const float* w2  = (const float*)d_in[3];
  const float* b2  = (const float*)d_in[4];
  const float* w3  = (const float*)d_in[5];
  const float* b3  = (const float*)d_in[6];
  const float* w4  = (const float*)d_in[7];
  const float* b4  = (const float*)d_in[8];
  const float* wl1 = (const float*)d_in[9];
  const float* bl1 = (const float*)d_in[10];
  const float* wl2 = (const float*)d_in[11];
  const float* bl2 = (const float*)d_in[12];
  float* out = (float*)d_out;
  char* ws = (char*)d_ws;

  // ws layout: apack @0 (194KB); wl1h @512KB (1MB); h1 @2MB (64MB);
  // h2 @69206016 (32MB); h3 @102760448 (8MB).
  f16* apack = (f16*)ws;
  f16* wl1h  = (f16*)(ws + 524288u);
  f16* h1 = (f16*)(ws + 2097152u);
  f16* h2 = (f16*)(ws + 69206016u);
  f16* h3 = (f16*)(ws + 102760448u);

  pack_all<<<445, 512, 0, stream>>>(w1, w2, w3, w4, wl1, apack, wl1h);
  conv1_mfma<<<dim3(4, 256), 512, 0, stream>>>(x, apack, b1, h1);
  conv2_roll<<<dim3(4, 256), 256, 0, stream>>>(h1, apack + 9 * 512, b2, h2);
  conv_shift32<64, 32, 32, 8, 144><<<dim3(4, 256), 256, 0, stream>>>(
      h2, apack + 45 * 512, b3, h3);
  tail_fused<<<256, 512, 0, stream>>>(h3, apack + 117 * 512, b4, wl1h,
                                      bl1, wl2, bl2, out);
}

// Round 22
// 218.981 us; speedup vs baseline: 1.2782x; 1.0014x over previous
//
#include <hip/hip_runtime.h>

// MFMA f16 conv pipeline — FINAL (round 22 = best verified config, 219.3us).
// Session: 1510us (fp32 VALU baseline) -> 219.3us (6.9x). Key wins: f16 MFMA
// conversion (r4), bank-conflict-free shuffle-transpose staging (r6), 32x32x16
// shape (r8), rolling 6-slot LDS window (r11), kernel fusion 7->5 launches +
// h4-in-LDS (r15). Falsified alternatives: dbuf (117us), LDS-free direct
// (568us), wave-private windows (161us) vs shared rolling window (95us).
// Remaining ~2x gap vs composite floor is the compiler's vmcnt(0) drain at
// every s_barrier — not removable at HIP source level (guide §5 m97-m141).
//
// Layouts (CDNA4):
//   16x16x32: A/B k=(lane>>4)*8+j, m/n=lane&15; D col=lane&15, row=(lane>>4)*4+reg
//   32x32x16: A/B k=(lane>>5)*8+j, m/n=lane&31; D col=lane&31,
//             row=(reg&3)+8*(reg>>2)+4*(lane>>5)

typedef _Float16 f16;
typedef _Float16 f16x8 __attribute__((ext_vector_type(8)));
typedef _Float16 f16x4 __attribute__((ext_vector_type(4)));
typedef float f32x4 __attribute__((ext_vector_type(4)));
typedef float f32x16 __attribute__((ext_vector_type(16)));

// ---------------- pack_all: conv A-frags + wl1 -> f16 -------------------------
__global__ __launch_bounds__(512)
void pack_all(const float* __restrict__ w1, const float* __restrict__ w2,
              const float* __restrict__ w3, const float* __restrict__ w4,
              const float* __restrict__ wl1, f16* __restrict__ apack,
              f16* __restrict__ wl1h) {
  if (blockIdx.x >= 189) {
    int i = ((blockIdx.x - 189) * 512 + threadIdx.x) * 4;   // 256 blocks
    float4 v = *(const float4*)(wl1 + i);
    f16x4 h = { (f16)v.x, (f16)v.y, (f16)v.z, (f16)v.w };
    *(f16x4*)(wl1h + i) = h;
    return;
  }
  int idx = blockIdx.x * 512 + threadIdx.x;
  int frag = idx >> 9;
  int e = idx & 511;
  int lane = e >> 3, j = e & 7;
  float v = 0.f;
  if (frag < 9) {
    int kh = frag / 3, kw = frag % 3;
    int oc = lane & 31;
    int ic = (lane >> 5) * 8 + j;
    if (ic < 12) v = w1[((oc * 12 + ic) * 3 + kh) * 3 + kw];
  } else if (frag < 45) {
    int f = frag - 9;            // conv2 32x32
    int ocg = f & 1;
    int sk = f >> 1;
    int ks = sk & 1, sh = sk >> 1;
    int kh = sh / 3, kw = sh % 3;
    int oc = ocg * 32 + (lane & 31);
    int ic = ks * 16 + (lane >> 5) * 8 + j;
    v = w2[((oc * 32 + ic) * 3 + kh) * 3 + kw];
  } else if (frag < 117) {
    int f = frag - 45;           // conv3 32x32
    int ocg = f & 1;
    int sk = f >> 1;
    int ks = sk & 3, sh = sk >> 2;
    int kh = sh / 3, kw = sh % 3;
    int oc = ocg * 32 + (lane & 31);
    int ic = ks * 16 + (lane >> 5) * 8 + j;
    v = w3[((oc * 64 + ic) * 3 + kh) * 3 + kw];
  } else {
    int f = frag - 117;          // conv4 16x16
    int sk = f >> 2, og = f & 3;
    int sh = sk >> 1, ks = sk & 1;
    int kh = sh / 3, kw = sh % 3;
    int row16 = lane & 15, kg = lane >> 4;
    int oc = og * 16 + row16;
    int ic = ks * 32 + kg * 8 + j;
    v = w4[((oc * 64 + ic) * 3 + kh) * 3 + kw];
  }
  apack[idx] = (f16)v;
}

// ---------------- conv1: 12ch fp32 NCHW -> 32ch NHWC f16, pool ----------------
// TPB=8 rolling 6-slot window, 32x32x16, kw-outer B-share.
__global__ __launch_bounds__(512)
void conv1_mfma(const float* __restrict__ x, const f16* __restrict__ apack,
                const float* __restrict__ bias, f16* __restrict__ hout) {
  constexpr int W = 128, H = 128;
  constexpr int PADB = 48, ROWB = 130 * PADB;
  constexpr int TPB = 8;
  __shared__ char smem[6 * ROWB];               // 37440 B
  const int tid = threadIdx.x;
  const int n = blockIdx.y;
  const int R0 = blockIdx.x * (TPB * 4);

  if (tid < 36) {
    int slot = tid / 6, r = tid % 6;
    int px = (r >= 3) ? 129 : 0;
    int ch = r % 3;
    *(float4*)(smem + slot * ROWB + px * PADB + ch * 16) =
        make_float4(0.f, 0.f, 0.f, 0.f);
  }

  const int g = tid >> 4;
  const int l16 = tid & 15;
  const int Q = l16 >> 2, q = l16 & 3;

  auto load_row = [&](int ri) -> float4 {
    float4 v = make_float4(0.f, 0.f, 0.f, 0.f);
    if (l16 < 12 && ri >= 0 && ri < H)
      v = *(const float4*)(x + ((size_t)(n * 12 + l16) * H + ri) * W + g * 4);
    return v;
  };
  auto xpose_write = [&](float4 av, int slot) {
    float4 t1, t2;
    {
      float sx = __shfl_xor(av.x, 1), sy = __shfl_xor(av.y, 1);
      float sz = __shfl_xor(av.z, 1), sw = __shfl_xor(av.w, 1);
      bool odd = q & 1;
      t1.x = odd ? sy : av.x;  t1.y = odd ? av.y : sx;
      t1.z = odd ? sw : av.z;  t1.w = odd ? av.w : sz;
    }
    {
      float sx = __shfl_xor(t1.x, 2), sy = __shfl_xor(t1.y, 2);
      float sz = __shfl_xor(t1.z, 2), sw = __shfl_xor(t1.w, 2);
      bool hi2 = q & 2;
      t2.x = hi2 ? sz : t1.x;  t2.y = hi2 ? sw : t1.y;
      t2.z = hi2 ? t1.z : sx;  t2.w = hi2 ? t1.w : sy;
    }
    f16x4 h = { (f16)t2.x, (f16)t2.y, (f16)t2.z, (f16)t2.w };
    *(f16x4*)(smem + slot * ROWB + (g * 4 + q + 1) * PADB + Q * 8) = h;
  };

  const int wv = tid >> 6, l = tid & 63;
  const int rp = wv >> 2;
  const int pxb = (wv & 3) * 32;
  const int rl0 = rp * 2;
  const int ln = l & 31;
  const int hi = l >> 5;

  f16x8 A[9];
#pragma unroll
  for (int ks = 0; ks < 9; ++ks)
    A[ks] = *(const f16x8*)(apack + ((ks << 9) + (l << 3)));

  float4 a[6];
#pragma unroll
  for (int i = 0; i < 6; ++i) a[i] = load_row(R0 - 1 + i);
#pragma unroll
  for (int i = 0; i < 6; ++i) xpose_write(a[i], i);
  __syncthreads();

  int s0 = 0;
  for (int t = 0; t < TPB; ++t) {
    if (t + 1 < TPB) {
#pragma unroll
      for (int i = 0; i < 4; ++i) a[i] = load_row(R0 + 4 * t + 5 + i);
    }
    f32x16 acc0 = (f32x16)0.f, acc1 = (f32x16)0.f;
#pragma unroll
    for (int kw = 0; kw < 3; ++kw) {
      const char* bcol = smem + (pxb + ln + kw) * PADB + hi * 16;
      f16x8 R[4];
#pragma unroll
      for (int j = 0; j < 4; ++j) {
        int sl = s0 + rl0 + j; if (sl >= 6) sl -= 6;
        R[j] = *(const f16x8*)(bcol + sl * ROWB);
      }
#pragma unroll
      for (int kh = 0; kh < 3; ++kh) {
        acc0 = __builtin_amdgcn_mfma_f32_32x32x16_f16(A[kh * 3 + kw], R[kh],     acc0, 0, 0, 0);
        acc1 = __builtin_amdgcn_mfma_f32_32x32x16_f16(A[kh * 3 + kw], R[kh + 1], acc1, 0, 0, 0);
      }
    }
    {
      const int pr = (R0 >> 1) + 2 * t + rp;
#pragma unroll
      for (int gg = 0; gg < 4; ++gg) {
        float v[4];
#pragma unroll
        for (int c = 0; c < 4; ++c) {
          float m = fmaxf(acc0[gg * 4 + c], acc1[gg * 4 + c]);
          v[c] = fmaxf(m, __shfl_xor(m, 1));
        }
        if ((l & 1) == 0) {
          const int pw = (pxb + ln) >> 1;
          const int oc0 = gg * 8 + hi * 4;
          f16x4 pk;
#pragma unroll
          for (int c = 0; c < 4; ++c)
            pk[c] = (f16)fmaxf(v[c] + bias[oc0 + c], 0.f);
          *(f16x4*)(hout + (((size_t)(n * 64 + pr) * 64 + pw) * 32 + oc0)) = pk;
        }
      }
    }
    __syncthreads();
    if (t + 1 < TPB) {
#pragma unroll
      for (int i = 0; i < 4; ++i) {
        int sl = s0 + i; if (sl >= 6) sl -= 6;
        xpose_write(a[i], sl);
      }
      __syncthreads();
    }
    s0 += 4; if (s0 >= 6) s0 -= 6;
  }
}

// ---------------- conv2: rolling-window multi-tile, 32x32x16 ------------------
__global__ __launch_bounds__(256)
void conv2_roll(const f16* __restrict__ hin, const f16* __restrict__ apack,
                const float* __restrict__ bias, f16* __restrict__ hout) {
  constexpr int C = 32, W = 64, H = 64;
  constexpr int PADB = 80, ROWB = 66 * PADB;
  constexpr int TPB = 4;
  __shared__ char smem[6 * ROWB];               // 31680 B
  const int tid = threadIdx.x;
  const int n = blockIdx.y;
  const int R0 = blockIdx.x * (TPB * 4);

  auto chunk_ld = [&](int c, int rbase) -> float4 {
    int rowl = c / 264, rem = c - rowl * 264;
    int px = rem >> 2, kc = rem & 3;
    int ri = rbase + rowl, gx = px - 1;
    float4 v = make_float4(0.f, 0.f, 0.f, 0.f);
    if (ri >= 0 && ri < H && gx >= 0 && gx < W)
      v = *(const float4*)(hin + (((size_t)(n * H + ri) * W + gx) * C + kc * 8));
    return v;
  };
  auto chunk_st = [&](int c, int sbase, float4 v) {
    int rowl = c / 264, rem = c - rowl * 264;
    int px = rem >> 2, kc = rem & 3;
    int slot = sbase + rowl; if (slot >= 6) slot -= 6;
    *(float4*)(smem + slot * ROWB + px * PADB + kc * 16) = v;
  };

  {
    float4 a[7];
#pragma unroll
    for (int it = 0; it < 7; ++it) {
      int c = tid + it * 256;
      a[it] = (c < 1584) ? chunk_ld(c, R0 - 1) : make_float4(0.f, 0.f, 0.f, 0.f);
    }
#pragma unroll
    for (int it = 0; it < 7; ++it) {
      int c = tid + it * 256;
      if (c < 1584) chunk_st(c, 0, a[it]);
    }
  }
  __syncthreads();

  const int wv = tid >> 6, l = tid & 63;
  const int rp = wv >> 1;
  const int pxb = (wv & 1) * 32;
  const int rl0 = rp * 2;
  const int ln = l & 31;
  const int hi = l >> 5;

  float4 a[5];
  int s04 = 0;
  for (int t = 0; t < TPB; ++t) {
    if (t + 1 < TPB) {
#pragma unroll
      for (int it = 0; it < 5; ++it) {
        int c = tid + it * 256;
        a[it] = (c < 1056) ? chunk_ld(c, R0 + 4 * t + 5)
                           : make_float4(0.f, 0.f, 0.f, 0.f);
      }
    }
    f32x16 acc[2][2];
    acc[0][0] = (f32x16)0.f; acc[0][1] = (f32x16)0.f;
    acc[1][0] = (f32x16)0.f; acc[1][1] = (f32x16)0.f;
#pragma unroll
    for (int sh = 0; sh < 9; ++sh) {
      const int kh = sh / 3, kw = sh % 3;
      f16x8 A[2][2];
#pragma unroll
      for (int ks = 0; ks < 2; ++ks)
#pragma unroll
        for (int ocg = 0; ocg < 2; ++ocg)
          A[ks][ocg] = *(const f16x8*)(apack + ((((sh * 2 + ks) * 2 + ocg) << 9) + (l << 3)));
#pragma unroll
      for (int rowi = 0; rowi < 2; ++rowi) {
        int sl = s04 + rl0 + rowi + kh; if (sl >= 6) sl -= 6;
        const char* base = smem + sl * ROWB + (pxb + ln + kw) * PADB + hi * 16;
#pragma unroll
        for (int ks = 0; ks < 2; ++ks) {
          f16x8 B = *(const f16x8*)(base + ks * 32);
          acc[rowi][0] = __builtin_amdgcn_mfma_f32_32x32x16_f16(A[ks][0], B, acc[rowi][0], 0, 0, 0);
          acc[rowi][1] = __builtin_amdgcn_mfma_f32_32x32x16_f16(A[ks][1], B, acc[rowi][1], 0, 0, 0);
        }
      }
    }
    {
      const int pr = (R0 >> 1) + 2 * t + rp;
#pragma unroll
      for (int ocg = 0; ocg < 2; ++ocg) {
#pragma unroll
        for (int gg = 0; gg < 4; ++gg) {
          float v[4];
#pragma unroll
          for (int c = 0; c < 4; ++c) {
            float m = fmaxf(acc[0][ocg][gg * 4 + c], acc[1][ocg][gg * 4 + c]);
            v[c] = fmaxf(m, __shfl_xor(m, 1));
          }
          if ((l & 1) == 0) {
            const int pw = (pxb + ln) >> 1;
            const int oc0 = ocg * 32 + gg * 8 + hi * 4;
            f16x4 pk;
#pragma unroll
            for (int c = 0; c < 4; ++c)
              pk[c] = (f16)fmaxf(v[c] + bias[oc0 + c], 0.f);
            *(f16x4*)(hout + (((size_t)(n * 32 + pr) * 32 + pw) * 64 + oc0)) = pk;
          }
        }
      }
    }
    __syncthreads();
    if (t + 1 < TPB) {
#pragma unroll
      for (int it = 0; it < 5; ++it) {
        int c = tid + it * 256;
        if (c < 1056) chunk_st(c, s04, a[it]);
      }
      __syncthreads();
    }
    s04 += 4; if (s04 >= 6) s04 -= 6;
  }
}

// ---------------- conv3: one-shot 32x32x16 ------------------------------------
template<int C, int W, int H, int BR, int PADB>
__global__ __launch_bounds__(256)
void conv_shift32(const f16* __restrict__ hin, const f16* __restrict__ apack,
                  const float* __restrict__ bias, f16* __restrict__ hout) {
  constexpr int KS16 = C / 16;
  constexpr int SR = BR + 2;
  constexpr int ROWB = (W + 2) * PADB;
  __shared__ char smem[SR * ROWB];
  const int tid = threadIdx.x;
  const int n = blockIdx.y;
  const int r0 = blockIdx.x * BR;
  constexpr int CPC = C / 8;
  constexpr int TOTC = SR * (W + 2) * CPC;
  constexpr int NITER = (TOTC + 255) / 256;
  {
    float4 stg[NITER];
#pragma unroll
    for (int it = 0; it < NITER; ++it) {
      const int t = tid + it * 256;
      float4 v = make_float4(0.f, 0.f, 0.f, 0.f);
      if (t < TOTC) {
        int sr = t / ((W + 2) * CPC);
        int rem = t - sr * ((W + 2) * CPC);
        int px = rem / CPC;
        int kc = rem - px * CPC;
        int ri = r0 + sr - 1;
        int gx = px - 1;
        if (ri >= 0 && ri < H && gx >= 0 && gx < W)
          v = *(const float4*)(hin + (((size_t)(n * H + ri) * W + gx) * C + kc * 8));
      }
      stg[it] = v;
    }
#pragma unroll
    for (int it = 0; it < NITER; ++it) {
      const int t = tid + it * 256;
      if (t < TOTC) {
        int sr = t / ((W + 2) * CPC);
        int rem = t - sr * ((W + 2) * CPC);
        int px = rem / CPC;
        int kc = rem - px * CPC;
        *(float4*)(smem + sr * ROWB + px * PADB + kc * 16) = stg[it];
      }
    }
  }
  __syncthreads();

  const int wv = tid >> 6, l = tid & 63;
  constexpr int WPP = W / 32;
  const int rp = wv / WPP;
  const int pxb = (wv % WPP) * 32;
  const int rl0 = rp * 2;
  const int ln = l & 31;
  const int hi = l >> 5;
  const int px0 = pxb + ln;

  f32x16 acc[2][2];
  acc[0][0] = (f32x16)0.f; acc[0][1] = (f32x16)0.f;
  acc[1][0] = (f32x16)0.f; acc[1][1] = (f32x16)0.f;

#pragma unroll
  for (int sh = 0; sh < 9; ++sh) {
    const int kh = sh / 3, kw = sh % 3;
    f16x8 A[KS16][2];
#pragma unroll
    for (int ks = 0; ks < KS16; ++ks)
#pragma unroll
      for (int ocg = 0; ocg < 2; ++ocg)
        A[ks][ocg] = *(const f16x8*)(apack + ((((sh * KS16 + ks) * 2 + ocg) << 9) + (l << 3)));
#pragma unroll
    for (int rowi = 0; rowi < 2; ++rowi) {
      const char* base = smem + (rl0 + rowi + kh) * ROWB + (px0 + kw) * PADB + hi * 16;
#pragma unroll
      for (int ks = 0; ks < KS16; ++ks) {
        f16x8 B = *(const f16x8*)(base + ks * 32);
        acc[rowi][0] = __builtin_amdgcn_mfma_f32_32x32x16_f16(A[ks][0], B, acc[rowi][0], 0, 0, 0);
        acc[rowi][1] = __builtin_amdgcn_mfma_f32_32x32x16_f16(A[ks][1], B, acc[rowi][1], 0, 0, 0);
      }
    }
  }
  constexpr int PH = H / 2, PW = W / 2;
  const int pr = blockIdx.x * (BR / 2) + rp;
#pragma unroll
  for (int ocg = 0; ocg < 2; ++ocg) {
#pragma unroll
    for (int gg = 0; gg < 4; ++gg) {
      float v[4];
#pragma unroll
      for (int c = 0; c < 4; ++c) {
        float m = fmaxf(acc[0][ocg][gg * 4 + c], acc[1][ocg][gg * 4 + c]);
        v[c] = fmaxf(m, __shfl_xor(m, 1));
      }
      if ((l & 1) == 0) {
        const int pw = (pxb + ln) >> 1;
        const int oc0 = ocg * 32 + gg * 8 + hi * 4;
        f16x4 pk;
#pragma unroll
        for (int c = 0; c < 4; ++c)
          pk[c] = (f16)fmaxf(v[c] + bias[oc0 + c], 0.f);
        *(f16x4*)(hout + (((size_t)(n * PH + pr) * PW + pw) * 64 + oc0)) = pk;
      }
    }
  }
}

// ---------------- tail_fused: conv4 + maxpool + FC head, one block per image --
__global__ __launch_bounds__(512)
void tail_fused(const f16* __restrict__ hin, const f16* __restrict__ apack4,
                const float* __restrict__ bias, const f16* __restrict__ wl1h,
                const float* __restrict__ bl1, const float* __restrict__ wl2,
                const float* __restrict__ bl2, float* __restrict__ out) {
  constexpr int C = 64, W = 16, H = 16;
  constexpr int PADB = 144, ROWB = 18 * PADB;   // 2592 B/row-slot
  __shared__ char smem[18 * ROWB];              // 46656 B
  __shared__ float hbuf[4096];
  __shared__ float red[4 * 128];
  __shared__ float red2[128];
  const int tid = threadIdx.x;
  const int n = blockIdx.x;

  constexpr int CPC = 8, TOTC = 18 * 18 * CPC;
  {
    float4 stg[6];
#pragma unroll
    for (int it = 0; it < 6; ++it) {
      const int t = tid + it * 512;
      float4 v = make_float4(0.f, 0.f, 0.f, 0.f);
      if (t < TOTC) {
        int sr = t / (18 * CPC);
        int rem = t - sr * (18 * CPC);
        int px = rem / CPC;
        int kc = rem - px * CPC;
        int ri = sr - 1, gx = px - 1;
        if (ri >= 0 && ri < H && gx >= 0 && gx < W)
          v = *(const float4*)(hin + (((size_t)(n * H + ri) * W + gx) * C + kc * 8));
      }
      stg[it] = v;
    }
#pragma unroll
    for (int it = 0; it < 6; ++it) {
      const int t = tid + it * 512;
      if (t < TOTC) {
        int sr = t / (18 * CPC);
        int rem = t - sr * (18 * CPC);
        int px = rem / CPC;
        int kc = rem - px * CPC;
        *(float4*)(smem + sr * ROWB + px * PADB + kc * 16) = stg[it];
      }
    }
  }
  __syncthreads();

  {
    const int wv = tid >> 6, l = tid & 63;
    const int lp = l & 15, kg = l >> 4;
    const int rl0 = wv * 2;

    f32x4 acc[2][4];
#pragma unroll
    for (int a = 0; a < 2; ++a)
#pragma unroll
      for (int o = 0; o < 4; ++o) acc[a][o] = (f32x4){0.f, 0.f, 0.f, 0.f};

#pragma unroll
    for (int sh = 0; sh < 9; ++sh) {
      const int kh = sh / 3, kw = sh % 3;
      f16x8 A[2][4];
#pragma unroll
      for (int ks = 0; ks < 2; ++ks)
#pragma unroll
        for (int og = 0; og < 4; ++og)
          A[ks][og] = *(const f16x8*)(apack4 + ((((sh * 2 + ks) * 4 + og) << 9) + (l << 3)));
#pragma unroll
      for (int rowi = 0; rowi < 2; ++rowi) {
        const char* base = smem + (rl0 + rowi + kh) * ROWB;
#pragma unroll
        for (int ks = 0; ks < 2; ++ks) {
          f16x8 B = *(const f16x8*)(base + (lp + kw) * PADB + ks * 64 + kg * 16);
#pragma unroll
          for (int og = 0; og < 4; ++og)
            acc[rowi][og] =
                __builtin_amdgcn_mfma_f32_16x16x32_f16(A[ks][og], B, acc[rowi][og], 0, 0, 0);
        }
      }
    }
#pragma unroll
    for (int og = 0; og < 4; ++og) {
      float v[4];
#pragma unroll
      for (int c = 0; c < 4; ++c) {
        float m = fmaxf(acc[0][og][c], acc[1][og][c]);
        v[c] = fmaxf(m, __shfl_xor(m, 1));
      }
      if ((l & 1) == 0) {
        const int pw = lp >> 1;
        const int oc0 = og * 16 + kg * 4;
#pragma unroll
        for (int c = 0; c < 4; ++c)
          hbuf[(oc0 + c) * 64 + wv * 8 + pw] = fmaxf(v[c] + bias[oc0 + c], 0.f);
      }
    }
  }
  __syncthreads();

  {
    const int nn = tid & 127;
    const int ks = tid >> 7;
    const f16x8* wp = (const f16x8*)(wl1h + (size_t)nn * 4096 + ks * 1024);
    const float4* xr = (const float4*)(&hbuf[ks * 1024]);
    float s = 0.f;
#pragma unroll 4
    for (int i = 0; i < 128; ++i) {
      f16x8 w8 = wp[i];
      float4 a0 = xr[2 * i], a1 = xr[2 * i + 1];
      s = fmaf((float)w8[0], a0.x, fmaf((float)w8[1], a0.y,
          fmaf((float)w8[2], a0.z, fmaf((float)w8[3], a0.w, s))));
      s = fmaf((float)w8[4], a1.x, fmaf((float)w8[5], a1.y,
          fmaf((float)w8[6], a1.z, fmaf((float)w8[7], a1.w, s))));
    }
    red[ks * 128 + nn] = s;
  }
  __syncthreads();
  if (tid < 128) {
    float h = bl1[tid] + red[tid] + red[128 + tid] + red[256 + tid] + red[384 + tid];
    h = fmaxf(h, 0.f);
    red2[tid] = h * (wl2[tid] + 20.0f * wl2[256 + tid]);
  }
  __syncthreads();
#pragma unroll
  for (int s = 64; s > 0; s >>= 1) {
    if (tid < s) red2[tid] += red2[tid + s];
    __syncthreads();
  }
  if (tid == 0) out[n] = red2[0] + bl2[0] + 20.0f * bl2[2];
}

extern "C" void kernel_launch(void* const* d_in, const int* in_sizes, int n_in,
                              void* d_out, int out_size, void* d_ws, size_t ws_size,
                              hipStream_t stream) {
  const float* x   = (const float*)d_in[0];
  const float* w1  = (const float*)d_in[1];
  const float* b1  = (const float*)d_in[2];
  const float* w2  = (const float*)d_in[3];
  const float* b2  = (const float*)d_in[4];
  const float* w3  = (const float*)d_in[5];
  const float* b3  = (const float*)d_in[6];
  const float* w4  = (const float*)d_in[7];
  const float* b4  = (const float*)d_in[8];
  const float* wl1 = (const float*)d_in[9];
  const float* bl1 = (const float*)d_in[10];
  const float* wl2 = (const float*)d_in[11];
  const float* bl2 = (const float*)d_in[12];
  float* out = (float*)d_out;
  char* ws = (char*)d_ws;

  // ws layout: apack @0 (194KB); wl1h @512KB (1MB); h1 @2MB (64MB);
  // h2 @69206016 (32MB); h3 @102760448 (8MB).
  f16* apack = (f16*)ws;
  f16* wl1h  = (f16*)(ws + 524288u);
  f16* h1 = (f16*)(ws + 2097152u);
  f16* h2 = (f16*)(ws + 69206016u);
  f16* h3 = (f16*)(ws + 102760448u);

  pack_all<<<445, 512, 0, stream>>>(w1, w2, w3, w4, wl1, apack, wl1h);
  conv1_mfma<<<dim3(4, 256), 512, 0, stream>>>(x, apack, b1, h1);
  conv2_roll<<<dim3(4, 256), 256, 0, stream>>>(h1, apack + 9 * 512, b2, h2);
  conv_shift32<64, 32, 32, 8, 144><<<dim3(4, 256), 256, 0, stream>>>(
      h2, apack + 45 * 512, b3, h3);
  tail_fused<<<256, 512, 0, stream>>>(h3, apack + 117 * 512, b4, wl1h,
                                      bl1, wl2, bl2, out);
}